// Round 2
// baseline (15813.637 us; speedup 1.0000x reference)
//
#include <hip/hip_runtime.h>
#include <math.h>

#define N 512
#define HALFR 256          // rows per block (matrix split across 2 blocks)
#define NITERS 100
#define CNT_OFF 4096       // float index (within matrix region) of pair counter
// floats [0..4095] of each matrix's output region double as the partial-exchange
// buffer during iterations: float2 part[half][parity][512]. Overwritten by the
// epilogue only after the final pair barrier.

__global__ void init_counters(float* P, int batch) {
    int m = blockIdx.x * blockDim.x + threadIdx.x;
    if (m < batch)
        *(unsigned int*)(P + (size_t)m * N * N + CNT_OFF) = 0u;
}

__global__ __launch_bounds__(1024, 1)
void sinkhorn_pair(const float* __restrict__ X, float* __restrict__ P) {
    __shared__ float u_s[HALFR];
    __shared__ float v_s[N];
    __shared__ float pm[1024];
    __shared__ float ps[1024];

    const int tid  = threadIdx.x;
    const int lane = tid & 63;
    const int wave = tid >> 6;            // 0..15
    const int m    = blockIdx.x >> 1;     // matrix index
    const int half = blockIdx.x & 1;      // which 256-row half we own

    const size_t base = (size_t)m * N * N;
    const float* __restrict__ A  = X + base + (size_t)half * HALFR * N;
    float*       __restrict__ out = P + base + (size_t)half * HALFR * N;
    float2* part = (float2*)(P + base);                     // [half][parity][col]
    unsigned int* cnt = (unsigned int*)(P + base + CNT_OFF);

    if (tid < N) v_s[tid] = 0.0f;
    __syncthreads();

    const float SC = 10.0f;   // 1 / ENTROPY_REG

    for (int it = 0; it < NITERS; ++it) {
        // ---- row pass over own rows: u_r = lse_j(A[r][j]*SC - v[j]) ----
        #pragma unroll 1
        for (int r = wave; r < HALFR; r += 16) {
            const float4* rowp = (const float4*)(A + (size_t)r * N);
            float4 a0 = rowp[lane];
            float4 a1 = rowp[lane + 64];
            float4 vv0 = *(const float4*)(v_s + 4 * lane);
            float4 vv1 = *(const float4*)(v_s + 256 + 4 * lane);
            float x0 = fmaf(a0.x, SC, -vv0.x);
            float x1 = fmaf(a0.y, SC, -vv0.y);
            float x2 = fmaf(a0.z, SC, -vv0.z);
            float x3 = fmaf(a0.w, SC, -vv0.w);
            float x4 = fmaf(a1.x, SC, -vv1.x);
            float x5 = fmaf(a1.y, SC, -vv1.y);
            float x6 = fmaf(a1.z, SC, -vv1.z);
            float x7 = fmaf(a1.w, SC, -vv1.w);
            float mx = fmaxf(fmaxf(fmaxf(x0, x1), fmaxf(x2, x3)),
                             fmaxf(fmaxf(x4, x5), fmaxf(x6, x7)));
            #pragma unroll
            for (int o = 32; o > 0; o >>= 1) mx = fmaxf(mx, __shfl_xor(mx, o, 64));
            float s = __expf(x0 - mx) + __expf(x1 - mx) + __expf(x2 - mx) + __expf(x3 - mx)
                    + __expf(x4 - mx) + __expf(x5 - mx) + __expf(x6 - mx) + __expf(x7 - mx);
            #pragma unroll
            for (int o = 32; o > 0; o >>= 1) s += __shfl_xor(s, o, 64);
            if (lane == 0) u_s[r] = mx + __logf(s);
        }
        __syncthreads();

        // ---- col pass over own 256 rows: partial lse per column ----
        {
            const int c  = tid & (N - 1);
            const int i0 = (tid >> 9) * (HALFR / 2);
            float mx = -1.0e30f, s = 0.0f;
            #pragma unroll 1
            for (int i = i0; i < i0 + HALFR / 2; i += 8) {
                float x[8];
                #pragma unroll
                for (int k = 0; k < 8; ++k)
                    x[k] = fmaf(A[(size_t)(i + k) * N + c], SC, -u_s[i + k]);
                float cm = x[0];
                #pragma unroll
                for (int k = 1; k < 8; ++k) cm = fmaxf(cm, x[k]);
                float mn = fmaxf(mx, cm);
                float acc = s * __expf(mx - mn);
                #pragma unroll
                for (int k = 0; k < 8; ++k) acc += __expf(x[k] - mn);
                mx = mn; s = acc;
            }
            pm[tid] = mx; ps[tid] = s;
        }
        __syncthreads();

        // merge two row-segments -> block partial; publish to partner
        const int c = tid & (N - 1);
        float bm = 0.f, bs = 0.f;
        if (tid < N) {
            float m0 = pm[tid],       s0 = ps[tid];
            float m1 = pm[tid + 512], s1 = ps[tid + 512];
            bm = fmaxf(m0, m1);
            bs = s0 * __expf(m0 - bm) + s1 * __expf(m1 - bm);
            part[(size_t)(half * 2 + (it & 1)) * N + c] = make_float2(bm, bs);
        }
        __syncthreads();   // all writes drained (waitcnt before s_barrier)

        // pair barrier: monotone counter, arrive + spin
        if (tid == 0) {
            atomicAdd(cnt, 1u);
            const unsigned int target = 2u * (unsigned)(it + 1);
            while (atomicAdd(cnt, 0u) < target) __builtin_amdgcn_s_sleep(2);
        }
        __syncthreads();
        __threadfence();   // acquire: invalidate L1 before reading partner data

        if (tid < N) {
            float2 o = part[(size_t)((1 - half) * 2 + (it & 1)) * N + c];
            float mn = fmaxf(bm, o.x);
            float sv = bs * __expf(bm - mn) + o.y * __expf(o.x - mn);
            v_s[c] = mn + __logf(sv);
        }
        __syncthreads();
    }

    // final pair barrier: partner must be done reading partials before the
    // half-0 epilogue overwrites the scratch region at P+base
    if (tid == 0) {
        atomicAdd(cnt, 1u);
        const unsigned int target = 2u * NITERS + 2u;
        while (atomicAdd(cnt, 0u) < target) __builtin_amdgcn_s_sleep(2);
    }
    __syncthreads();

    // ---- epilogue: P = exp(A*SC - u_r - v_c) over own rows ----
    #pragma unroll 1
    for (int r = wave; r < HALFR; r += 16) {
        const float ur = u_s[r];
        const float4* rowp = (const float4*)(A + (size_t)r * N);
        float4* outp = (float4*)(out + (size_t)r * N);
        float4 a0 = rowp[lane];
        float4 a1 = rowp[lane + 64];
        float4 vv0 = *(const float4*)(v_s + 4 * lane);
        float4 vv1 = *(const float4*)(v_s + 256 + 4 * lane);
        float4 o0, o1;
        o0.x = __expf(fmaf(a0.x, SC, -vv0.x) - ur);
        o0.y = __expf(fmaf(a0.y, SC, -vv0.y) - ur);
        o0.z = __expf(fmaf(a0.z, SC, -vv0.z) - ur);
        o0.w = __expf(fmaf(a0.w, SC, -vv0.w) - ur);
        o1.x = __expf(fmaf(a1.x, SC, -vv1.x) - ur);
        o1.y = __expf(fmaf(a1.y, SC, -vv1.y) - ur);
        o1.z = __expf(fmaf(a1.z, SC, -vv1.z) - ur);
        o1.w = __expf(fmaf(a1.w, SC, -vv1.w) - ur);
        outp[lane]      = o0;
        outp[lane + 64] = o1;
    }
}

extern "C" void kernel_launch(void* const* d_in, const int* in_sizes, int n_in,
                              void* d_out, int out_size, void* d_ws, size_t ws_size,
                              hipStream_t stream) {
    const float* X = (const float*)d_in[0];
    float* P = (float*)d_out;
    const int batch = in_sizes[0] / (N * N);   // 128

    hipLaunchKernelGGL(init_counters, dim3((batch + 127) / 128), dim3(128), 0, stream,
                       P, batch);

    void* args[] = { (void*)&X, (void*)&P };
    hipLaunchCooperativeKernel((const void*)sinkhorn_pair,
                               dim3(2 * batch), dim3(1024), args, 0, stream);
}

// Round 3
// 2436.086 us; speedup vs baseline: 6.4914x; 6.4914x over previous
//
#include <hip/hip_runtime.h>
#include <math.h>

#define N 512
#define NITERS 100

// One block (1024 thr, 16 waves) per matrix. Fused Sinkhorn iteration:
// single pass over A per iteration:
//   per row r (wave-parallel): x_j = A_rj*SC - v_j ; m = max_j x ; e = exp(x-m);
//   S = sum e ; (row now normalized: P_row = e/S)
//   column partials: c_j += e_j / S   (linear, bounded by #rows -> no lse)
// then v_j += log(c_j). u only needed for the epilogue -> computed last iter.
__global__ __launch_bounds__(1024, 1)
void sinkhorn_fused(const float* __restrict__ X, float* __restrict__ P) {
    __shared__ float v_s[N];
    __shared__ float u_s[N];
    __shared__ float c_lds[16 * N];   // [wave][col]

    const int tid  = threadIdx.x;
    const int lane = tid & 63;
    const int wave = tid >> 6;            // 0..15

    const size_t base = (size_t)blockIdx.x * N * N;
    const float* __restrict__ A = X + base;
    float* __restrict__ out = P + base;

    if (tid < N) v_s[tid] = 0.0f;
    __syncthreads();

    const float SC = 10.0f;   // 1 / ENTROPY_REG
    // row stride between this wave's consecutive rows: 16 rows
    const size_t RSTEP = (size_t)16 * N;

    for (int it = 0; it < NITERS; ++it) {
        float4 vv0 = *(const float4*)(v_s + 4 * lane);
        float4 vv1 = *(const float4*)(v_s + 256 + 4 * lane);
        float c0 = 0.f, c1 = 0.f, c2 = 0.f, c3 = 0.f,
              c4 = 0.f, c5 = 0.f, c6 = 0.f, c7 = 0.f;
        const bool last = (it == NITERS - 1);

        // software-pipelined row loop: rows wave, wave+16, ..., 32 rows/wave
        const float* rp = A + (size_t)wave * N;
        float4 a0 = ((const float4*)rp)[lane];
        float4 a1 = ((const float4*)rp)[lane + 64];

        #pragma unroll 1
        for (int r = wave; r < N; r += 16) {
            // prefetch next row while reducing current
            float4 b0, b1;
            if (r + 16 < N) {
                const float4* np = (const float4*)(rp + RSTEP);
                b0 = np[lane];
                b1 = np[lane + 64];
            }
            float x0 = fmaf(a0.x, SC, -vv0.x);
            float x1 = fmaf(a0.y, SC, -vv0.y);
            float x2 = fmaf(a0.z, SC, -vv0.z);
            float x3 = fmaf(a0.w, SC, -vv0.w);
            float x4 = fmaf(a1.x, SC, -vv1.x);
            float x5 = fmaf(a1.y, SC, -vv1.y);
            float x6 = fmaf(a1.z, SC, -vv1.z);
            float x7 = fmaf(a1.w, SC, -vv1.w);
            float mx = fmaxf(fmaxf(fmaxf(x0, x1), fmaxf(x2, x3)),
                             fmaxf(fmaxf(x4, x5), fmaxf(x6, x7)));
            #pragma unroll
            for (int o = 32; o > 0; o >>= 1) mx = fmaxf(mx, __shfl_xor(mx, o, 64));
            float e0 = __expf(x0 - mx), e1 = __expf(x1 - mx);
            float e2 = __expf(x2 - mx), e3 = __expf(x3 - mx);
            float e4 = __expf(x4 - mx), e5 = __expf(x5 - mx);
            float e6 = __expf(x6 - mx), e7 = __expf(x7 - mx);
            float s = ((e0 + e1) + (e2 + e3)) + ((e4 + e5) + (e6 + e7));
            #pragma unroll
            for (int o = 32; o > 0; o >>= 1) s += __shfl_xor(s, o, 64);
            float invS = __builtin_amdgcn_rcpf(s);
            c0 = fmaf(e0, invS, c0); c1 = fmaf(e1, invS, c1);
            c2 = fmaf(e2, invS, c2); c3 = fmaf(e3, invS, c3);
            c4 = fmaf(e4, invS, c4); c5 = fmaf(e5, invS, c5);
            c6 = fmaf(e6, invS, c6); c7 = fmaf(e7, invS, c7);
            if (last && lane == 0) u_s[r] = mx + __logf(s);
            a0 = b0; a1 = b1;
            rp += RSTEP;
        }

        // publish column partials, reduce across 16 waves
        *(float4*)(c_lds + wave * N + 4 * lane)       = make_float4(c0, c1, c2, c3);
        *(float4*)(c_lds + wave * N + 256 + 4 * lane) = make_float4(c4, c5, c6, c7);
        __syncthreads();
        if (tid < N) {
            float cs = 0.f;
            #pragma unroll
            for (int w = 0; w < 16; ++w) cs += c_lds[w * N + tid];
            v_s[tid] += __logf(fmaxf(cs, 1e-30f));
        }
        __syncthreads();
    }

    // ---- epilogue: P = exp(A*SC - u_r - v_c) (one extra read of A) ----
    {
        float4 vv0 = *(const float4*)(v_s + 4 * lane);
        float4 vv1 = *(const float4*)(v_s + 256 + 4 * lane);
        #pragma unroll 1
        for (int r = wave; r < N; r += 16) {
            const float ur = u_s[r];
            const float4* rowp = (const float4*)(A + (size_t)r * N);
            float4* outp = (float4*)(out + (size_t)r * N);
            float4 a0 = rowp[lane];
            float4 a1 = rowp[lane + 64];
            float4 o0, o1;
            o0.x = __expf(fmaf(a0.x, SC, -vv0.x) - ur);
            o0.y = __expf(fmaf(a0.y, SC, -vv0.y) - ur);
            o0.z = __expf(fmaf(a0.z, SC, -vv0.z) - ur);
            o0.w = __expf(fmaf(a0.w, SC, -vv0.w) - ur);
            o1.x = __expf(fmaf(a1.x, SC, -vv1.x) - ur);
            o1.y = __expf(fmaf(a1.y, SC, -vv1.y) - ur);
            o1.z = __expf(fmaf(a1.z, SC, -vv1.z) - ur);
            o1.w = __expf(fmaf(a1.w, SC, -vv1.w) - ur);
            outp[lane]      = o0;
            outp[lane + 64] = o1;
        }
    }
}

extern "C" void kernel_launch(void* const* d_in, const int* in_sizes, int n_in,
                              void* d_out, int out_size, void* d_ws, size_t ws_size,
                              hipStream_t stream) {
    const float* X = (const float*)d_in[0];
    float* P = (float*)d_out;
    const int batch = in_sizes[0] / (N * N);   // 128
    hipLaunchKernelGGL(sinkhorn_fused, dim3(batch), dim3(1024), 0, stream, X, P);
}

// Round 4
// 2183.489 us; speedup vs baseline: 7.2424x; 1.1157x over previous
//
#include <hip/hip_runtime.h>
#include <math.h>

#define N 512
#define NITERS 100
#define SC 10.0f

// round-to-nearest-even fp32 -> bf16 pair packed into one uint
__device__ __forceinline__ unsigned int pack_bf16(float a, float b) {
    unsigned int ua = __float_as_uint(a);
    unsigned int ub = __float_as_uint(b);
    ua = (ua + 0x7fffu + ((ua >> 16) & 1u)) >> 16;
    ub = (ub + 0x7fffu + ((ub >> 16) & 1u)) >> 16;
    return ua | (ub << 16);
}

// One block (1024 thr) per matrix. Multiplicative Sinkhorn on a precomputed
// bf16 kernel matrix K' = exp(A*SC - rowmax_i) (constant across iterations):
//   row pass: S_i = sum_j K'_ij w_j ; col pass: c_j = sum_i K'_ij w_j / S_i ;
//   w_j <- w_j / c_j.  No exp/log/max in the iteration loop at all.
// Final P_ij = exp(A_ij*SC - m_i - lnS_i + ln w_j)  (recomputed from fp32 A).
// K' is stored in the FIRST 512KB of this block's own output region, so the
// epilogue's P writes only clobber our own (already consumed) K'.
__global__ __launch_bounds__(1024, 1)
void sinkhorn_mult(const float* __restrict__ X, float* __restrict__ P) {
    __shared__ float w_s[N];        // column scaling w = exp(-v)
    __shared__ float m_s[N];        // rowmax of A*SC
    __shared__ float lnS_s[N];      // ln(row sum) at final row pass
    __shared__ float c_lds[16 * N]; // per-wave column partials

    const int tid  = threadIdx.x;
    const int lane = tid & 63;
    const int wave = tid >> 6;          // 0..15

    const size_t base = (size_t)blockIdx.x * N * N;
    const float* __restrict__ A   = X + base;
    float*       __restrict__ out = P + base;
    unsigned short* __restrict__ Kb = (unsigned short*)(P + base);  // 512 KB, own region

    if (tid < N) w_s[tid] = 1.0f;

    // ---- precompute K' = exp(A*SC - rowmax) in bf16; rowmax -> m_s ----
    #pragma unroll 1
    for (int r = wave; r < N; r += 16) {
        const float4* rowp = (const float4*)(A + (size_t)r * N);
        float4 a0 = rowp[lane];          // cols 4L..4L+3
        float4 a1 = rowp[lane + 64];     // cols 256+4L..
        float x0 = a0.x * SC, x1 = a0.y * SC, x2 = a0.z * SC, x3 = a0.w * SC;
        float x4 = a1.x * SC, x5 = a1.y * SC, x6 = a1.z * SC, x7 = a1.w * SC;
        float mx = fmaxf(fmaxf(fmaxf(x0, x1), fmaxf(x2, x3)),
                         fmaxf(fmaxf(x4, x5), fmaxf(x6, x7)));
        #pragma unroll
        for (int o = 32; o > 0; o >>= 1) mx = fmaxf(mx, __shfl_xor(mx, o, 64));
        uint2 p0, p1;
        p0.x = pack_bf16(__expf(x0 - mx), __expf(x1 - mx));
        p0.y = pack_bf16(__expf(x2 - mx), __expf(x3 - mx));
        p1.x = pack_bf16(__expf(x4 - mx), __expf(x5 - mx));
        p1.y = pack_bf16(__expf(x6 - mx), __expf(x7 - mx));
        uint2* krow = (uint2*)(Kb + (size_t)r * N);
        krow[lane]      = p0;            // bf16 cols 4L..4L+3
        krow[lane + 64] = p1;            // bf16 cols 256+4L..
        if (lane == 0) m_s[r] = mx;
    }
    __threadfence();     // own global writes visible before block re-reads
    __syncthreads();

    // ---- 100 multiplicative iterations: pure mul/add on bf16 K' ----
    const size_t RSTEP = (size_t)16 * N;   // ushorts
    for (int it = 0; it < NITERS; ++it) {
        float4 w0 = *(const float4*)(w_s + 8 * lane);       // cols 8L..8L+3
        float4 w1 = *(const float4*)(w_s + 8 * lane + 4);   // cols 8L+4..8L+7
        float c0 = 0.f, c1 = 0.f, c2 = 0.f, c3 = 0.f,
              c4 = 0.f, c5 = 0.f, c6 = 0.f, c7 = 0.f;
        const bool last = (it == NITERS - 1);

        const unsigned short* kp = Kb + (size_t)wave * N;
        uint4 kq = ((const uint4*)kp)[lane];   // 8 bf16: cols 8L..8L+7
        #pragma unroll 1
        for (int r = wave; r < N; r += 16) {
            uint4 nq;
            if (r + 16 < N) nq = ((const uint4*)(kp + RSTEP))[lane];
            float f0 = __uint_as_float(kq.x << 16);
            float f1 = __uint_as_float(kq.x & 0xffff0000u);
            float f2 = __uint_as_float(kq.y << 16);
            float f3 = __uint_as_float(kq.y & 0xffff0000u);
            float f4 = __uint_as_float(kq.z << 16);
            float f5 = __uint_as_float(kq.z & 0xffff0000u);
            float f6 = __uint_as_float(kq.w << 16);
            float f7 = __uint_as_float(kq.w & 0xffff0000u);
            float e0 = f0 * w0.x, e1 = f1 * w0.y, e2 = f2 * w0.z, e3 = f3 * w0.w;
            float e4 = f4 * w1.x, e5 = f5 * w1.y, e6 = f6 * w1.z, e7 = f7 * w1.w;
            float s = ((e0 + e1) + (e2 + e3)) + ((e4 + e5) + (e6 + e7));
            #pragma unroll
            for (int o = 32; o > 0; o >>= 1) s += __shfl_xor(s, o, 64);
            float invS = __builtin_amdgcn_rcpf(s);
            c0 = fmaf(e0, invS, c0); c1 = fmaf(e1, invS, c1);
            c2 = fmaf(e2, invS, c2); c3 = fmaf(e3, invS, c3);
            c4 = fmaf(e4, invS, c4); c5 = fmaf(e5, invS, c5);
            c6 = fmaf(e6, invS, c6); c7 = fmaf(e7, invS, c7);
            if (last && lane == 0) lnS_s[r] = __logf(s);
            kq = nq; kp += RSTEP;
        }

        *(float4*)(c_lds + wave * N + 8 * lane)     = make_float4(c0, c1, c2, c3);
        *(float4*)(c_lds + wave * N + 8 * lane + 4) = make_float4(c4, c5, c6, c7);
        __syncthreads();
        if (tid < N) {
            float cs = 0.f;
            #pragma unroll
            for (int w = 0; w < 16; ++w) cs += c_lds[w * N + tid];
            w_s[tid] = w_s[tid] / fmaxf(cs, 1e-38f);
        }
        __syncthreads();
    }

    // ---- epilogue: P = exp(A*SC - m_i - lnS_i + ln w_j) from fp32 A ----
    float* g_s  = c_lds;        // ln w  [N]
    float* rt_s = c_lds + N;    // -(m + lnS) [N]
    if (tid < N) {
        g_s[tid]  = __logf(w_s[tid]);
        rt_s[tid] = -(m_s[tid] + lnS_s[tid]);
    }
    __syncthreads();

    #pragma unroll 1
    for (int r = wave; r < N; r += 16) {
        const float rt = rt_s[r];
        const float4* rowp = (const float4*)(A + (size_t)r * N);
        float4 a0 = rowp[lane];
        float4 a1 = rowp[lane + 64];
        float4 g0 = *(const float4*)(g_s + 4 * lane);
        float4 g1 = *(const float4*)(g_s + 256 + 4 * lane);
        float4 o0, o1;
        o0.x = __expf(fmaf(a0.x, SC, rt) + g0.x);
        o0.y = __expf(fmaf(a0.y, SC, rt) + g0.y);
        o0.z = __expf(fmaf(a0.z, SC, rt) + g0.z);
        o0.w = __expf(fmaf(a0.w, SC, rt) + g0.w);
        o1.x = __expf(fmaf(a1.x, SC, rt) + g1.x);
        o1.y = __expf(fmaf(a1.y, SC, rt) + g1.y);
        o1.z = __expf(fmaf(a1.z, SC, rt) + g1.z);
        o1.w = __expf(fmaf(a1.w, SC, rt) + g1.w);
        float4* outp = (float4*)(out + (size_t)r * N);
        outp[lane]      = o0;
        outp[lane + 64] = o1;
    }
}

extern "C" void kernel_launch(void* const* d_in, const int* in_sizes, int n_in,
                              void* d_out, int out_size, void* d_ws, size_t ws_size,
                              hipStream_t stream) {
    const float* X = (const float*)d_in[0];
    float* P = (float*)d_out;
    const int batch = in_sizes[0] / (N * N);   // 128
    hipLaunchKernelGGL(sinkhorn_mult, dim3(batch), dim3(1024), 0, stream, X, P);
}